// Round 9
// baseline (160.794 us; speedup 1.0000x reference)
//
#include <hip/hip_runtime.h>
#include <hip/hip_bf16.h>
#include <stdint.h>
#include <string.h>

typedef __attribute__((ext_vector_type(8))) short short8;   // 8 bf16 (4 VGPRs) MFMA operand
typedef __attribute__((ext_vector_type(4))) float floatx4;  // MFMA accumulator

#define NPTS 256   // points per group
#define DIM  256   // feature dim
#define TILE 128   // output tile per block

// packed fp32->bf16 RNE; returns packed pair, accumulates squared sum of the
// ROUNDED values (consistent metric between Gram term and norms).
static __device__ __forceinline__ uint32_t cvtsq2(float a, float b, float& s) {
    __hip_bfloat162 h = __float22bfloat162_rn(float2{a, b});
    uint32_t d;
    memcpy(&d, &h, 4);
    const float lo = __builtin_bit_cast(float, d << 16);
    const float hi = __builtin_bit_cast(float, d & 0xFFFF0000u);
    s += lo * lo + hi * hi;
    return d;
}

// ---------------------------------------------------------------------------
// Kernel 1: fp32 -> bf16 (RNE) materialization + squared norms of the rounded
// points. One wave per point, 16 points per 256-thread block.
// SWZ=true (G==128): group g is processed by blocks with blockIdx%8 == g%8,
// matching the gemm's read swizzle -> the dirty-L2 handoff is XCD-local.
// ---------------------------------------------------------------------------
template<bool SWZ>
__global__ __launch_bounds__(256)
void mmd_cvt(const float* __restrict__ X, const float* __restrict__ Y,
             float* __restrict__ x2, float* __restrict__ y2,
             uint16_t* __restrict__ Xb, uint16_t* __restrict__ Yb, int npts) {
    const int lane = threadIdx.x & 63;
    const int wv   = threadIdx.x >> 6;
    int pblk;
    if (SWZ) {
        // 4096 blocks: x = XCD, q>>5 selects one of 16 groups on this XCD,
        // c = q&31 selects 16-point chunk (c<16 -> X side, else Y side).
        const int d = blockIdx.x, x = d & 7, q = d >> 3;
        const int g = (q >> 5) * 8 + x;
        const int c = q & 31;
        pblk = (c < 16) ? (g * NPTS + c * 16)
                        : (npts + g * NPTS + (c - 16) * 16);
    } else {
        pblk = blockIdx.x * 16;
    }
    #pragma unroll
    for (int r = 0; r < 4; ++r) {
        const int p = pblk + wv + 4 * r;     // chunk never straddles X/Y
        const float* src; float* dst; uint16_t* bdst; int pl;
        if (p < npts) { src = X; dst = x2; bdst = Xb; pl = p; }
        else          { src = Y; dst = y2; bdst = Yb; pl = p - npts; }
        const float4 v = *(const float4*)(src + (size_t)pl * DIM + lane * 4);
        float ssq = 0.0f;
        uint2 pk;
        pk.x = cvtsq2(v.x, v.y, ssq);
        pk.y = cvtsq2(v.z, v.w, ssq);
        *(uint2*)(bdst + (size_t)pl * DIM + lane * 4) = pk;
        #pragma unroll
        for (int off = 32; off; off >>= 1) ssq += __shfl_down(ssq, off);
        if (lane == 0) dst[pl] = ssq;
    }
}

// ---------------------------------------------------------------------------
// Kernel 2: barrier-free, LDS-free Gram GEMM with FULL-K fragment preload.
// All 64 fragment loads (whole K=256) issue up front into ~256 VGPRs ->
// one latency exposure per block instead of eight (round-8's wall: with the
// 128-reg occupancy cap the compiler couldn't hoist anything and every
// K-iter ate a full L2/L3 latency). 1 wave/SIMD; MFMA phase shadows the
// tail of the loads. grid = 10*G XCD-swizzled; t 0..3 = XY (w=+1),
// 4..6 = XX upper-tri (w=-0.5/-1/-0.5, off-diag double via w), 7..9 = YY.
// ---------------------------------------------------------------------------
__global__ __launch_bounds__(256)
void mmd_gemm(const uint16_t* __restrict__ Xb, const uint16_t* __restrict__ Yb,
              const float* __restrict__ x2, const float* __restrict__ y2,
              float* __restrict__ out, float scale, int G) {
    int g, t;
    const int f = blockIdx.x;
    if ((G & 7) == 0) { const int xcd = f & 7, j = f >> 3; g = (j / 10) * 8 + xcd; t = j % 10; }
    else              { g = f / 10; t = f % 10; }

    int ptype, ti, tj; float w;
    if (t < 4)      { ptype = 0; ti = t >> 1; tj = t & 1; w = 1.0f; }
    else if (t < 7) { int u = t - 4; ptype = 1; ti = (u == 2); tj = (u >= 1); w = (u == 1) ? -1.0f : -0.5f; }
    else            { int u = t - 7; ptype = 2; ti = (u == 2); tj = (u >= 1); w = (u == 1) ? -1.0f : -0.5f; }

    const uint16_t *Pb, *Qb; const float *rn_g, *cn_g;
    if (ptype == 0)      { Pb = Xb; Qb = Yb; rn_g = x2; cn_g = y2; }
    else if (ptype == 1) { Pb = Xb; Qb = Xb; rn_g = x2; cn_g = x2; }
    else                 { Pb = Yb; Qb = Yb; rn_g = y2; cn_g = y2; }
    const bool symdiag = (ptype != 0) && (ti == tj);

    const size_t prow0 = (size_t)g * NPTS + (size_t)ti * TILE;
    const size_t qrow0 = (size_t)g * NPTS + (size_t)tj * TILE;

    const int tid  = threadIdx.x;
    const int lane = tid & 63;
    const int wv   = tid >> 6;
    const int wrow = (wv >> 1) * 64;
    const int wcol = (wv & 1) * 64;
    const int quad = lane >> 4;
    const int l15  = lane & 15;

    // per-lane fragment base pointers: each fragment = 16 contiguous bytes;
    // K offsets (0..448 B) fold into the 13-bit imm offset of the load.
    const uint16_t* pa[4];
    const uint16_t* pb[4];
    #pragma unroll
    for (int mi = 0; mi < 4; ++mi)
        pa[mi] = Pb + (prow0 + wrow + mi * 16 + l15) * DIM + quad * 8;
    #pragma unroll
    for (int ni = 0; ni < 4; ++ni)
        pb[ni] = Qb + (qrow0 + wcol + ni * 16 + l15) * DIM + quad * 8;

    // ---- issue ALL 64 fragment loads (whole K) ----
    short8 A0[4][4], B0[4][4], A1[4][4], B1[4][4];   // [k-iter][frag]
    #pragma unroll
    for (int i = 0; i < 4; ++i) {
        #pragma unroll
        for (int mi = 0; mi < 4; ++mi) A0[i][mi] = *(const short8*)(pa[mi] + i * 32);
        #pragma unroll
        for (int ni = 0; ni < 4; ++ni) B0[i][ni] = *(const short8*)(pb[ni] + i * 32);
    }
    #pragma unroll
    for (int i = 0; i < 4; ++i) {
        #pragma unroll
        for (int mi = 0; mi < 4; ++mi) A1[i][mi] = *(const short8*)(pa[mi] + 128 + i * 32);
        #pragma unroll
        for (int ni = 0; ni < 4; ++ni) B1[i][ni] = *(const short8*)(pb[ni] + 128 + i * 32);
    }

    floatx4 acc[4][4];
    #pragma unroll
    for (int i = 0; i < 4; ++i)
        #pragma unroll
        for (int j = 0; j < 4; ++j) acc[i][j] = (floatx4)0.0f;

    // ---- 128 MFMAs; later loads complete under the MFMA shadow ----
    #pragma unroll
    for (int i = 0; i < 4; ++i)
        #pragma unroll
        for (int mi = 0; mi < 4; ++mi)
            #pragma unroll
            for (int ni = 0; ni < 4; ++ni)
                acc[mi][ni] = __builtin_amdgcn_mfma_f32_16x16x32_bf16(
                    A0[i][mi], B0[i][ni], acc[mi][ni], 0, 0, 0);
    #pragma unroll
    for (int i = 0; i < 4; ++i)
        #pragma unroll
        for (int mi = 0; mi < 4; ++mi)
            #pragma unroll
            for (int ni = 0; ni < 4; ++ni)
                acc[mi][ni] = __builtin_amdgcn_mfma_f32_16x16x32_bf16(
                    A1[i][mi], B1[i][ni], acc[mi][ni], 0, 0, 0);

    // col norms: c = wcol+ni*16+l15 -> coalesced 16-float loads
    float cn[4];
    #pragma unroll
    for (int ni = 0; ni < 4; ++ni) cn[ni] = cn_g[qrow0 + wcol + ni * 16 + l15];

    // fused epilogue: d = sqrt(max(x2_i + y2_j - 2 S_ij, 0)), diag zeroed for XX/YY
    // C/D layout: col = lane&15, row = (lane>>4)*4 + reg.
    float lsum = 0.0f;
    #pragma unroll
    for (int mi = 0; mi < 4; ++mi) {
        #pragma unroll
        for (int i = 0; i < 4; ++i) {
            const int r = wrow + mi * 16 + quad * 4 + i;
            const float rv = rn_g[prow0 + r];          // wave-broadcast, L1-hit
            #pragma unroll
            for (int ni = 0; ni < 4; ++ni) {
                const int c = wcol + ni * 16 + l15;
                float d2 = rv + cn[ni] - 2.0f * acc[mi][ni][i];
                float s = sqrtf(fmaxf(d2, 0.0f));
                if (symdiag && (r == c)) s = 0.0f;
                lsum += s;
            }
        }
    }
    #pragma unroll
    for (int off = 32; off; off >>= 1) lsum += __shfl_down(lsum, off);

    __shared__ float wpart[4];
    if (lane == 0) wpart[wv] = lsum;
    __syncthreads();
    if (tid == 0) {
        const float bs = wpart[0] + wpart[1] + wpart[2] + wpart[3];
        atomicAdd(out, bs * (w * scale));
    }
}

// ---------------------------------------------------------------------------
// Fallback (tiny workspace): round-7's fused pipeline (proven 52 us).
// ---------------------------------------------------------------------------
#define BK   32
#define LDSS 40
#define LDS_BARRIER() asm volatile("s_waitcnt lgkmcnt(0)\n\ts_barrier" ::: "memory")
static __device__ __forceinline__ uint4 cvt8(const float4 u, const float4 v, float& s) {
    uint4 r;
    r.x = cvtsq2(u.x, u.y, s); r.y = cvtsq2(u.z, u.w, s);
    r.z = cvtsq2(v.x, v.y, s); r.w = cvtsq2(v.z, v.w, s);
    return r;
}
__global__ __launch_bounds__(512, 4)
void mmd_pipe(const float* __restrict__ X, const float* __restrict__ Y,
              float* __restrict__ out, float scale, int G) {
    int g, t;
    const int f = blockIdx.x;
    if ((G & 7) == 0) { const int xcd = f & 7, j = f >> 3; g = (j / 10) * 8 + xcd; t = j % 10; }
    else              { g = f / 10; t = f % 10; }
    int ptype, ti, tj; float w;
    if (t < 4)      { ptype = 0; ti = t >> 1; tj = t & 1; w = 1.0f; }
    else if (t < 7) { int u = t - 4; ptype = 1; ti = (u == 2); tj = (u >= 1); w = (u == 1) ? -1.0f : -0.5f; }
    else            { int u = t - 7; ptype = 2; ti = (u == 2); tj = (u >= 1); w = (u == 1) ? -1.0f : -0.5f; }
    const float *Pf, *Qf;
    if (ptype == 0)      { Pf = X; Qf = Y; }
    else if (ptype == 1) { Pf = X; Qf = X; }
    else                 { Pf = Y; Qf = Y; }
    const bool symdiag = (ptype != 0) && (ti == tj);
    const size_t prow0 = (size_t)g * NPTS + (size_t)ti * TILE;
    const size_t qrow0 = (size_t)g * NPTS + (size_t)tj * TILE;
    __shared__ __align__(16) uint16_t As[2][TILE * LDSS];
    __shared__ __align__(16) uint16_t Bs[2][TILE * LDSS];
    __shared__ float rnorm[TILE]; __shared__ float cnorm[TILE]; __shared__ float wpart[8];
    const int tid = threadIdx.x, lane = tid & 63, wv = tid >> 6;
    const int quad = lane >> 4, l15 = lane & 15;
    const int rowbase = (wv & 3) * 32, colbase = (wv >> 2) * 64;
    const int prow = tid >> 2, pcol = (tid & 3) * 8;
    const float* gA = Pf + (prow0 + prow) * DIM + pcol;
    const float* gB = Qf + (qrow0 + prow) * DIM + pcol;
    const int woff = prow * LDSS + pcol;
    floatx4 acc[2][4];
    #pragma unroll
    for (int i = 0; i < 2; ++i)
        #pragma unroll
        for (int j = 0; j < 4; ++j) acc[i][j] = (floatx4)0.0f;
    float sqp = 0.0f, sqq = 0.0f;
    float4 ra0 = *(const float4*)(gA), ra1 = *(const float4*)(gA + 4);
    float4 rb0 = *(const float4*)(gB), rb1 = *(const float4*)(gB + 4);
    { const uint4 pa = cvt8(ra0, ra1, sqp); const uint4 pb = cvt8(rb0, rb1, sqq);
      *(uint4*)&As[0][woff] = pa; *(uint4*)&Bs[0][woff] = pb; }
    ra0 = *(const float4*)(gA + BK); ra1 = *(const float4*)(gA + BK + 4);
    rb0 = *(const float4*)(gB + BK); rb1 = *(const float4*)(gB + BK + 4);
    #pragma unroll
    for (int it = 0; it < DIM / BK; ++it) {
        const int b = it & 1;
        LDS_BARRIER();
        if (it < DIM / BK - 1) {
            const uint4 pa = cvt8(ra0, ra1, sqp); const uint4 pb = cvt8(rb0, rb1, sqq);
            *(uint4*)&As[b ^ 1][woff] = pa; *(uint4*)&Bs[b ^ 1][woff] = pb;
        }
        if (it < DIM / BK - 2) {
            const int k0 = (it + 2) * BK;
            ra0 = *(const float4*)(gA + k0); ra1 = *(const float4*)(gA + k0 + 4);
            rb0 = *(const float4*)(gB + k0); rb1 = *(const float4*)(gB + k0 + 4);
        }
        short8 af[2], bfr[4];
        #pragma unroll
        for (int mi = 0; mi < 2; ++mi)
            af[mi] = *(const short8*)&As[b][(rowbase + mi * 16 + l15) * LDSS + quad * 8];
        #pragma unroll
        for (int ni = 0; ni < 4; ++ni)
            bfr[ni] = *(const short8*)&Bs[b][(colbase + ni * 16 + l15) * LDSS + quad * 8];
        #pragma unroll
        for (int mi = 0; mi < 2; ++mi)
            #pragma unroll
            for (int ni = 0; ni < 4; ++ni)
                acc[mi][ni] = __builtin_amdgcn_mfma_f32_16x16x32_bf16(
                    af[mi], bfr[ni], acc[mi][ni], 0, 0, 0);
    }
    sqp += __shfl_xor(sqp, 1); sqp += __shfl_xor(sqp, 2);
    sqq += __shfl_xor(sqq, 1); sqq += __shfl_xor(sqq, 2);
    if ((tid & 3) == 0) { rnorm[prow] = sqp; cnorm[prow] = sqq; }
    __syncthreads();
    float lsum = 0.0f;
    #pragma unroll
    for (int mi = 0; mi < 2; ++mi)
        #pragma unroll
        for (int i = 0; i < 4; ++i) {
            const int r = rowbase + mi * 16 + quad * 4 + i;
            const float rv = rnorm[r];
            #pragma unroll
            for (int ni = 0; ni < 4; ++ni) {
                const int c = colbase + ni * 16 + l15;
                float d2 = rv + cnorm[c] - 2.0f * acc[mi][ni][i];
                float s = sqrtf(fmaxf(d2, 0.0f));
                if (symdiag && (r == c)) s = 0.0f;
                lsum += s;
            }
        }
    #pragma unroll
    for (int off = 32; off; off >>= 1) lsum += __shfl_down(lsum, off);
    if (lane == 0) wpart[wv] = lsum;
    __syncthreads();
    if (tid == 0) {
        float bs = 0.0f;
        #pragma unroll
        for (int i = 0; i < 8; ++i) bs += wpart[i];
        atomicAdd(out, bs * (w * scale));
    }
}

// ---------------------------------------------------------------------------
extern "C" void kernel_launch(void* const* d_in, const int* in_sizes, int n_in,
                              void* d_out, int out_size, void* d_ws, size_t ws_size,
                              hipStream_t stream) {
    const float* X = (const float*)d_in[0];
    const float* Y = (const float*)d_in[1];
    const int total_elems = in_sizes[0];          // G*NPTS*DIM
    const int npts = total_elems / DIM;
    const int G = npts / NPTS;

    float* out = (float*)d_out;
    hipMemsetAsync(out, 0, sizeof(float) * out_size, stream);
    const float scale = 1.0f / ((float)NPTS * (float)NPTS * (float)G);

    float* x2 = (float*)d_ws;
    float* y2 = x2 + npts;
    uint16_t* Xb = (uint16_t*)(y2 + npts);
    uint16_t* Yb = Xb + (size_t)total_elems;
    const size_t need = (size_t)npts * 2 * sizeof(float)
                      + (size_t)total_elems * 2 * sizeof(uint16_t);

    if (ws_size >= need) {
        if (G == 128) mmd_cvt<true ><<<(2 * npts) / 16, 256, 0, stream>>>(X, Y, x2, y2, Xb, Yb, npts);
        else          mmd_cvt<false><<<(2 * npts) / 16, 256, 0, stream>>>(X, Y, x2, y2, Xb, Yb, npts);
        mmd_gemm<<<10 * G, 256, 0, stream>>>(Xb, Yb, x2, y2, out, scale, G);
    } else {
        mmd_pipe<<<10 * G, 512, 0, stream>>>(X, Y, out, scale, G);
    }
}

// Round 10
// 131.943 us; speedup vs baseline: 1.2187x; 1.2187x over previous
//
#include <hip/hip_runtime.h>
#include <hip/hip_bf16.h>
#include <stdint.h>
#include <string.h>

typedef __attribute__((ext_vector_type(8))) short short8;   // 8 bf16 (4 VGPRs) MFMA operand
typedef __attribute__((ext_vector_type(4))) float floatx4;  // MFMA accumulator

#define NPTS 256   // points per group
#define DIM  256   // feature dim
#define TILE 128   // output tile per block
#define BK   64    // K-step (4 iterations over DIM=256)
#define NIT  (DIM / BK)
#define LDSS 72    // LDS row stride in bf16 elems (144 B rows, 16B-aligned)

// Workgroup barrier WITHOUT the vmcnt(0) drain __syncthreads() forces.
// LDS producer->consumer ordering needs only lgkmcnt(0); in-flight global
// prefetches (private VGPR destinations) survive the barrier.
#define LDS_BARRIER() asm volatile("s_waitcnt lgkmcnt(0)\n\ts_barrier" ::: "memory")

// packed fp32->bf16 RNE convert; accumulates squared sum of the ROUNDED
// values (consistent metric between Gram term and norms).
static __device__ __forceinline__ uint32_t cvtsq2(float a, float b, float& s) {
    __hip_bfloat162 h = __float22bfloat162_rn(float2{a, b});
    uint32_t d;
    memcpy(&d, &h, 4);
    const float lo = __builtin_bit_cast(float, d << 16);
    const float hi = __builtin_bit_cast(float, d & 0xFFFF0000u);
    s += lo * lo + hi * hi;
    return d;
}

// ---------------------------------------------------------------------------
// Fused energy-distance kernel, round-5 structure with COALESCED staging:
// each staging load instruction covers 4 rows x 256 B contiguous (4 segments)
// instead of r5's 16 rows x small chunks (16 segments) -> ~4x less TA/L1
// address-path pressure, which rounds 4-9 identify as the binding resource.
// grid = 10*G XCD-swizzled: t 0..3 = XY (w=+1), 4..6 = XX upper-tri
// (w=-0.5/-1/-0.5, off-diag double-counted via w), 7..9 = YY upper-tri.
// ---------------------------------------------------------------------------
__global__ __launch_bounds__(512)
void mmd_pipe(const float* __restrict__ X, const float* __restrict__ Y,
              float* __restrict__ out, float scale, int G) {
    // ---- block -> (group, tile) decode with XCD swizzle ----
    int g, t;
    const int f = blockIdx.x;
    if ((G & 7) == 0) { const int xcd = f & 7, j = f >> 3; g = (j / 10) * 8 + xcd; t = j % 10; }
    else              { g = f / 10; t = f % 10; }

    int ptype, ti, tj; float w;
    if (t < 4)      { ptype = 0; ti = t >> 1; tj = t & 1; w = 1.0f; }
    else if (t < 7) { int u = t - 4; ptype = 1; ti = (u == 2); tj = (u >= 1); w = (u == 1) ? -1.0f : -0.5f; }
    else            { int u = t - 7; ptype = 2; ti = (u == 2); tj = (u >= 1); w = (u == 1) ? -1.0f : -0.5f; }

    const float *Pf, *Qf;
    if (ptype == 0)      { Pf = X; Qf = Y; }
    else if (ptype == 1) { Pf = X; Qf = X; }
    else                 { Pf = Y; Qf = Y; }
    const bool symdiag = (ptype != 0) && (ti == tj);

    const size_t prow0 = (size_t)g * NPTS + (size_t)ti * TILE;
    const size_t qrow0 = (size_t)g * NPTS + (size_t)tj * TILE;

    __shared__ __align__(16) uint16_t As[2][TILE * LDSS];  // 2 x 18 KB
    __shared__ __align__(16) uint16_t Bs[2][TILE * LDSS];
    __shared__ float rnorm[TILE];
    __shared__ float cnorm[TILE];
    __shared__ float wpart[8];

    const int tid  = threadIdx.x;          // 0..511
    const int lane = tid & 63;
    const int wv   = tid >> 6;             // 0..7
    const int quad = lane >> 4;
    const int l15  = lane & 15;
    const int rowbase = (wv & 3) * 32;     // wave's 32-row stripe (output)
    const int colbase = (wv >> 2) * 64;    // wave's 64-col stripe (output)

    // ---- staging geometry: 16 consecutive threads cover one row's 64-float
    //      K-chunk (4 floats each) -> 4 rows x 256 B contiguous per wave-inst.
    const int trow = tid >> 4;             // 0..31; pass p adds 32*p
    const int tcol = (tid & 15) * 4;       // fp32 col within chunk
    const float* gA = Pf + (prow0 + trow) * DIM + tcol;
    const float* gB = Qf + (qrow0 + trow) * DIM + tcol;
    const int woff = trow * LDSS + tcol;   // bf16-elem LDS offset (pass adds 32*LDSS)

    floatx4 acc[2][4];
    #pragma unroll
    for (int i = 0; i < 2; ++i)
        #pragma unroll
        for (int j = 0; j < 4; ++j) acc[i][j] = (floatx4)0.0f;

    // per-thread partial row norms: sq?[p] belongs to row trow + 32*p
    float sqa[4] = {0.f, 0.f, 0.f, 0.f};
    float sqb[4] = {0.f, 0.f, 0.f, 0.f};

    float4 ra[4], rb[4];

    // ---- prologue: stage chunk 0 into LDS[0] ----
    #pragma unroll
    for (int p = 0; p < 4; ++p) {
        ra[p] = *(const float4*)(gA + p * (32 * DIM));
        rb[p] = *(const float4*)(gB + p * (32 * DIM));
    }
    #pragma unroll
    for (int p = 0; p < 4; ++p) {
        uint2 wa, wb;
        wa.x = cvtsq2(ra[p].x, ra[p].y, sqa[p]);
        wa.y = cvtsq2(ra[p].z, ra[p].w, sqa[p]);
        wb.x = cvtsq2(rb[p].x, rb[p].y, sqb[p]);
        wb.y = cvtsq2(rb[p].z, rb[p].w, sqb[p]);
        *(uint2*)&As[0][woff + p * (32 * LDSS)] = wa;
        *(uint2*)&Bs[0][woff + p * (32 * LDSS)] = wb;
    }

    // ---- main loop: barrier -> issue loads(it+1) -> MFMA(it) -> write(it+1)
    #pragma unroll
    for (int it = 0; it < NIT; ++it) {
        const int b = it & 1;
        LDS_BARRIER();                      // LDS[b] visible to all waves

        if (it < NIT - 1) {                 // issue coalesced loads for chunk it+1
            const int kk = (it + 1) * BK;
            #pragma unroll
            for (int p = 0; p < 4; ++p) {
                ra[p] = *(const float4*)(gA + kk + p * (32 * DIM));
                rb[p] = *(const float4*)(gB + kk + p * (32 * DIM));
            }
        }

        // consume chunk it from LDS[b]: 2 k-steps of 32
        #pragma unroll
        for (int ks = 0; ks < 2; ++ks) {
            const int kof = ks * 32 + quad * 8;
            short8 af[2], bfr[4];
            #pragma unroll
            for (int mi = 0; mi < 2; ++mi)
                af[mi] = *(const short8*)&As[b][(rowbase + mi * 16 + l15) * LDSS + kof];
            #pragma unroll
            for (int ni = 0; ni < 4; ++ni)
                bfr[ni] = *(const short8*)&Bs[b][(colbase + ni * 16 + l15) * LDSS + kof];
            #pragma unroll
            for (int mi = 0; mi < 2; ++mi)
                #pragma unroll
                for (int ni = 0; ni < 4; ++ni)
                    acc[mi][ni] = __builtin_amdgcn_mfma_f32_16x16x32_bf16(
                        af[mi], bfr[ni], acc[mi][ni], 0, 0, 0);
        }

        if (it < NIT - 1) {                 // convert + write chunk it+1 into LDS[b^1]
            #pragma unroll
            for (int p = 0; p < 4; ++p) {
                uint2 wa, wb;
                wa.x = cvtsq2(ra[p].x, ra[p].y, sqa[p]);
                wa.y = cvtsq2(ra[p].z, ra[p].w, sqa[p]);
                wb.x = cvtsq2(rb[p].x, rb[p].y, sqb[p]);
                wb.y = cvtsq2(rb[p].z, rb[p].w, sqb[p]);
                *(uint2*)&As[b ^ 1][woff + p * (32 * LDSS)] = wa;
                *(uint2*)&Bs[b ^ 1][woff + p * (32 * LDSS)] = wb;
            }
        }
    }

    // ---- assemble norms: rows share 16 consecutive lanes -> xor-reduce ----
    #pragma unroll
    for (int p = 0; p < 4; ++p) {
        #pragma unroll
        for (int m = 1; m < 16; m <<= 1) {
            sqa[p] += __shfl_xor(sqa[p], m);
            sqb[p] += __shfl_xor(sqb[p], m);
        }
    }
    if ((tid & 15) == 0) {
        #pragma unroll
        for (int p = 0; p < 4; ++p) {
            rnorm[trow + 32 * p] = sqa[p];
            cnorm[trow + 32 * p] = sqb[p];
        }
    }
    __syncthreads();

    // ---- fused epilogue: d = sqrt(max(x2_i + y2_j - 2 S_ij, 0)) ----
    // C/D layout: col = lane&15, row = (lane>>4)*4 + reg.
    float lsum = 0.0f;
    #pragma unroll
    for (int mi = 0; mi < 2; ++mi) {
        #pragma unroll
        for (int i = 0; i < 4; ++i) {
            const int r = rowbase + mi * 16 + quad * 4 + i;
            const float rv = rnorm[r];
            #pragma unroll
            for (int ni = 0; ni < 4; ++ni) {
                const int c = colbase + ni * 16 + l15;
                float d2 = rv + cnorm[c] - 2.0f * acc[mi][ni][i];
                float s = sqrtf(fmaxf(d2, 0.0f));
                if (symdiag && (r == c)) s = 0.0f;
                lsum += s;
            }
        }
    }
    #pragma unroll
    for (int off = 32; off; off >>= 1) lsum += __shfl_down(lsum, off);
    if (lane == 0) wpart[wv] = lsum;
    __syncthreads();
    if (tid == 0) {
        float bs = 0.0f;
        #pragma unroll
        for (int i = 0; i < 8; ++i) bs += wpart[i];
        atomicAdd(out, bs * (w * scale));
    }
}

// ---------------------------------------------------------------------------
extern "C" void kernel_launch(void* const* d_in, const int* in_sizes, int n_in,
                              void* d_out, int out_size, void* d_ws, size_t ws_size,
                              hipStream_t stream) {
    const float* X = (const float*)d_in[0];
    const float* Y = (const float*)d_in[1];
    const int total_elems = in_sizes[0];          // G*NPTS*DIM
    const int G = total_elems / (NPTS * DIM);     // 128

    float* out = (float*)d_out;
    hipMemsetAsync(out, 0, sizeof(float) * out_size, stream);

    const float scale = 1.0f / ((float)NPTS * (float)NPTS * (float)G);
    mmd_pipe<<<10 * G, 512, 0, stream>>>(X, Y, out, scale, G);
}